// Round 1
// 843.314 us; speedup vs baseline: 1.0307x; 1.0307x over previous
//
#include <hip/hip_runtime.h>
#include <math.h>

#define D 256        // embedding dim
#define P 128        // projection dim
#define K 8192       // num embeddings
#define NTOK 16384   // 16*1024 tokens
#define NROWS (NTOK + K)
#define CAPC 64              // candidate slots per token (expect ~15-30 w/ running thr)
#define MARGIN 3.0f          // >> 2*bf16 distance error
#define FLT_BIG 3.402823466e+38f

typedef __attribute__((ext_vector_type(8))) short bf16x8;
typedef __attribute__((ext_vector_type(4))) float f32x4;
typedef __attribute__((ext_vector_type(8))) unsigned short u16x8;

__device__ __forceinline__ unsigned short f32_to_bf16_rne(float f) {
    unsigned int u = __float_as_uint(f);
    u = (u + 0x7fffu + ((u >> 16) & 1u)) >> 16;
    return (unsigned short)u;
}

// ---------------------------------------------------------------------------
// Kernel 1: fused projection (proven rounds 3-10). fp32 proj + norms; bf16
// copies (xh row-major; chs in MFMA-fragment-contiguous order). Inits cnt[].
// ARITHMETIC ORDER UNCHANGED.
// ---------------------------------------------------------------------------
__global__ __launch_bounds__(256) void proj_kernel(
    const float* __restrict__ x, const float* __restrict__ cb,
    const float* __restrict__ w, const float* __restrict__ bias,
    float* __restrict__ xproj, float* __restrict__ cproj,
    float* __restrict__ xnorm, float* __restrict__ cnorm,
    unsigned short* __restrict__ xh, unsigned short* __restrict__ chs,
    int* __restrict__ cnt)
{
    __shared__ float As[16][D];   // 16 KB
    const int tid = threadIdx.x;
    const int row0 = blockIdx.x * 16;

    {   // init counters (ws is poisoned each call)
        int g = blockIdx.x * 256 + tid;
        if (g < NTOK) cnt[g] = 0;
    }

    for (int i = tid; i < 16 * (D / 4); i += 256) {
        int r = i / (D / 4);
        int c4 = i % (D / 4);
        int gr = row0 + r;
        const float* src = (gr < NTOK) ? (x + (size_t)gr * D)
                                       : (cb + (size_t)(gr - NTOK) * D);
        float4 v = ((const float4*)src)[c4];
        ((float4*)&As[r][0])[c4] = v;
    }
    __syncthreads();

    const int r = tid >> 4;          // 0..15
    const int c0 = (tid & 15) * 8;   // 0..120

    float acc[8];
#pragma unroll
    for (int j = 0; j < 8; j++) acc[j] = 0.f;

    for (int d = 0; d < D; d += 4) {
        float4 a4 = *(const float4*)&As[r][d];
#pragma unroll
        for (int dd = 0; dd < 4; dd++) {
            float av = (dd == 0) ? a4.x : (dd == 1) ? a4.y : (dd == 2) ? a4.z : a4.w;
            float4 w0 = *(const float4*)&w[(size_t)(d + dd) * P + c0];
            float4 w1 = *(const float4*)&w[(size_t)(d + dd) * P + c0 + 4];
            acc[0] = fmaf(av, w0.x, acc[0]);
            acc[1] = fmaf(av, w0.y, acc[1]);
            acc[2] = fmaf(av, w0.z, acc[2]);
            acc[3] = fmaf(av, w0.w, acc[3]);
            acc[4] = fmaf(av, w1.x, acc[4]);
            acc[5] = fmaf(av, w1.y, acc[5]);
            acc[6] = fmaf(av, w1.z, acc[6]);
            acc[7] = fmaf(av, w1.w, acc[7]);
        }
    }

    float out[8];
    float nrm = 0.f;
    u16x8 hv;
#pragma unroll
    for (int j = 0; j < 8; j++) {
        out[j] = acc[j] + bias[c0 + j];
        nrm = fmaf(out[j], out[j], nrm);
        hv[j] = f32_to_bf16_rne(out[j]);
    }

    const int gr = row0 + r;
    float4 o0; o0.x = out[0]; o0.y = out[1]; o0.z = out[2]; o0.w = out[3];
    float4 o1; o1.x = out[4]; o1.y = out[5]; o1.z = out[6]; o1.w = out[7];
    if (gr < NTOK) {
        float* dst = xproj + (size_t)gr * P;
        *(float4*)&dst[c0] = o0;
        *(float4*)&dst[c0 + 4] = o1;
        *(u16x8*)(xh + (size_t)gr * P + c0) = hv;
    } else {
        int row = gr - NTOK;
        float* dst = cproj + (size_t)row * P;
        *(float4*)&dst[c0] = o0;
        *(float4*)&dst[c0 + 4] = o1;
        int t64 = row >> 6, rg = (row >> 4) & 3, rl = row & 15;
        int ks = c0 >> 5, q = (c0 >> 3) & 3;
        size_t atom = ((size_t)(t64 * 16 + rg * 4 + ks) * 4 + q) * 16 + rl;
        *(u16x8*)(chs + atom * 8) = hv;
    }

#pragma unroll
    for (int off = 1; off < 16; off <<= 1)
        nrm += __shfl_xor(nrm, off, 16);
    if ((tid & 15) == 0) {
        if (gr < NTOK) xnorm[gr] = nrm;
        else           cnorm[gr - NTOK] = nrm;
    }
}

// ---------------------------------------------------------------------------
// Kernel 2 (FUSED min + collect + zero-fill): single MFMA pass.  Emission
// threshold = running group min + MARGIN.  running_min >= final_min at all
// times, so the candidate set is a superset of {k : d_bf(k) <= gmin+2eps},
// hence contains the exact fp32 argmin — same correctness envelope as the
// old 2-pass scheme.  Running min is butterfly-shared across the 16-lane
// token group after ct0 (tight first threshold) and every 2nd ct after.
// Overflow past CAPC is handled by rescore's brute-force fallback.
// ---------------------------------------------------------------------------
__global__ __launch_bounds__(256, 3) void minzero_collect_kernel(
    const unsigned short* __restrict__ xh, const unsigned short* __restrict__ chs,
    const float* __restrict__ xnorm, const float* __restrict__ cnorm,
    int* __restrict__ cnt, int* __restrict__ cand, float* __restrict__ discrete)
{
    const int tid = threadIdx.x;
    const int tok0 = blockIdx.x * 128;
    const int kbase = blockIdx.y * 2048;
    const int flat = blockIdx.y * gridDim.x + blockIdx.x;   // 0..511

    const int wave = tid >> 6;
    const int lane = tid & 63;
    const int quad = lane >> 4;
    const int l15 = lane & 15;
    const int trow = tok0 + wave * 32;

    f32x4* zbase = (f32x4*)discrete + (size_t)flat * 65536;
    const f32x4 zv = (f32x4)(0.f);

    bf16x8 afrag[2][4];
#pragma unroll
    for (int mi = 0; mi < 2; mi++)
#pragma unroll
        for (int ks = 0; ks < 4; ks++)
            afrag[mi][ks] = *(const bf16x8*)(
                xh + (size_t)(trow + mi * 16 + l15) * P + ks * 32 + quad * 8);

    float xnv[2][4];
#pragma unroll
    for (int mi = 0; mi < 2; mi++)
#pragma unroll
        for (int r = 0; r < 4; r++)
            xnv[mi][r] = xnorm[trow + mi * 16 + quad * 4 + r];

    float rmin[2][4];
#pragma unroll
    for (int mi = 0; mi < 2; mi++)
#pragma unroll
        for (int r = 0; r < 4; r++) rmin[mi][r] = FLT_BIG;

    for (int ct = 0; ct < 32; ct++) {
        const int kt = kbase + ct * 64;
        const int t64 = kt >> 6;

#pragma unroll
        for (int s = 0; s < 8; s++)
            zbase[(size_t)ct * 2048 + s * 256 + tid] = zv;

        f32x4 acc[2][4];
#pragma unroll
        for (int mi = 0; mi < 2; mi++)
#pragma unroll
            for (int nj = 0; nj < 4; nj++) acc[mi][nj] = (f32x4)(0.f);

#pragma unroll
        for (int ks = 0; ks < 4; ks++) {
            const bf16x8* base = (const bf16x8*)(chs) + (size_t)(t64 * 16 + ks) * 64 + lane;
            bf16x8 b0 = base[0 * 4 * 64];
            bf16x8 b1 = base[1 * 4 * 64];
            bf16x8 b2 = base[2 * 4 * 64];
            bf16x8 b3 = base[3 * 4 * 64];
            acc[0][0] = __builtin_amdgcn_mfma_f32_16x16x32_bf16(afrag[0][ks], b0, acc[0][0], 0, 0, 0);
            acc[0][1] = __builtin_amdgcn_mfma_f32_16x16x32_bf16(afrag[0][ks], b1, acc[0][1], 0, 0, 0);
            acc[0][2] = __builtin_amdgcn_mfma_f32_16x16x32_bf16(afrag[0][ks], b2, acc[0][2], 0, 0, 0);
            acc[0][3] = __builtin_amdgcn_mfma_f32_16x16x32_bf16(afrag[0][ks], b3, acc[0][3], 0, 0, 0);
            acc[1][0] = __builtin_amdgcn_mfma_f32_16x16x32_bf16(afrag[1][ks], b0, acc[1][0], 0, 0, 0);
            acc[1][1] = __builtin_amdgcn_mfma_f32_16x16x32_bf16(afrag[1][ks], b1, acc[1][1], 0, 0, 0);
            acc[1][2] = __builtin_amdgcn_mfma_f32_16x16x32_bf16(afrag[1][ks], b2, acc[1][2], 0, 0, 0);
            acc[1][3] = __builtin_amdgcn_mfma_f32_16x16x32_bf16(afrag[1][ks], b3, acc[1][3], 0, 0, 0);
        }

        float cn[4];
#pragma unroll
        for (int nj = 0; nj < 4; nj++) cn[nj] = cnorm[kt + nj * 16 + l15];

        if (ct == 0) {
            // First tile: min pass -> butterfly share -> emit (tight threshold).
#pragma unroll
            for (int mi = 0; mi < 2; mi++)
#pragma unroll
                for (int r = 0; r < 4; r++) {
                    float rm = rmin[mi][r];
#pragma unroll
                    for (int nj = 0; nj < 4; nj++) {
                        float dd = (xnv[mi][r] - 2.0f * acc[mi][nj][r]) + cn[nj];
                        rm = fminf(rm, dd);
                    }
#pragma unroll
                    for (int off = 1; off < 16; off <<= 1)
                        rm = fminf(rm, __shfl_xor(rm, off));
                    rmin[mi][r] = rm;
                    const float thr = rm + MARGIN;
                    const int tok = trow + mi * 16 + quad * 4 + r;
#pragma unroll
                    for (int nj = 0; nj < 4; nj++) {
                        float dd = (xnv[mi][r] - 2.0f * acc[mi][nj][r]) + cn[nj];
                        if (dd <= thr) {
                            int pos = atomicAdd(&cnt[tok], 1);
                            if (pos < CAPC) cand[(size_t)tok * CAPC + pos] = kt + nj * 16 + l15;
                        }
                    }
                }
        } else {
            // Steady state: single pass.  thr uses the running min as of loop
            // entry (>= final min -> superset-safe); rm keeps improving.
#pragma unroll
            for (int mi = 0; mi < 2; mi++)
#pragma unroll
                for (int r = 0; r < 4; r++) {
                    float rm = rmin[mi][r];
                    const float thr = rm + MARGIN;
                    const int tok = trow + mi * 16 + quad * 4 + r;
#pragma unroll
                    for (int nj = 0; nj < 4; nj++) {
                        float dd = (xnv[mi][r] - 2.0f * acc[mi][nj][r]) + cn[nj];
                        rm = fminf(rm, dd);
                        if (dd <= thr) {
                            int pos = atomicAdd(&cnt[tok], 1);
                            if (pos < CAPC) cand[(size_t)tok * CAPC + pos] = kt + nj * 16 + l15;
                        }
                    }
                    rmin[mi][r] = rm;
                }
            if (ct & 1) {   // share group min every 2nd tile
#pragma unroll
                for (int mi = 0; mi < 2; mi++)
#pragma unroll
                    for (int r = 0; r < 4; r++) {
                        float m = rmin[mi][r];
#pragma unroll
                        for (int off = 1; off < 16; off <<= 1)
                            m = fminf(m, __shfl_xor(m, off));
                        rmin[mi][r] = m;
                    }
            }
        }
    }
}

// ---------------------------------------------------------------------------
// Kernel 3: fused exact-fp32 rescore + argmin + one-hot scatter + gather
// (proven round 9).  Packed u64 (dist_bits<<32|k): dist>0 -> monotone bits;
// tie -> lower idx (= jnp.argmin).  Bit-identical serial-fma order.
// NEW: if a token's candidate list overflowed CAPC, brute-force rescore all
// K codes (exact, data-independent safety net; never expected to trigger).
// ---------------------------------------------------------------------------
__global__ __launch_bounds__(256) void rescorefinal_kernel(
    const float* __restrict__ xproj, const float* __restrict__ cproj,
    const float* __restrict__ xnorm, const float* __restrict__ cnorm,
    const int* __restrict__ cnt, const int* __restrict__ cand,
    const float* __restrict__ cb,
    float* __restrict__ discrete, float* __restrict__ quant)
{
    __shared__ int sidx[64];
    const int tid = threadIdx.x;
    const int lane = tid & 63;
    const int wave = tid >> 6;
    const int tok0 = blockIdx.x * 64;

    for (int i = 0; i < 16; i++) {
        const int t = tok0 + wave * 16 + i;
        const int n = cnt[t];
        const bool full = (n > CAPC);     // overflow -> exact full scan
        const int lim = full ? K : n;
        const float xn = xnorm[t];
        const float* xr = xproj + (size_t)t * P;

        unsigned long long pack = 0xFFFFFFFFFFFFFFFFull;
        for (int j = lane; j < lim; j += 64) {
            const int k = full ? j : cand[(size_t)t * CAPC + j];
            const float* cr = cproj + (size_t)k * P;
            float s = 0.f;
#pragma unroll 8
            for (int p = 0; p < P; p += 4) {
                float4 a = *(const float4*)&xr[p];
                float4 b = *(const float4*)&cr[p];
                s = fmaf(a.x, b.x, s);
                s = fmaf(a.y, b.y, s);
                s = fmaf(a.z, b.z, s);
                s = fmaf(a.w, b.w, s);
            }
            float dist = (xn - 2.0f * s) + cnorm[k];
            unsigned long long pk =
                ((unsigned long long)__float_as_uint(dist) << 32) |
                (unsigned long long)(unsigned)k;
            if (pk < pack) pack = pk;
        }
#pragma unroll
        for (int off = 1; off < 64; off <<= 1) {
            unsigned long long o = __shfl_xor((long long)pack, off);
            if (o < pack) pack = o;
        }
        if (lane == 0) {
            int bi = (int)(pack & 0xFFFFFFFFull);
            if (bi >= 0 && bi < K) {
                sidx[wave * 16 + i] = bi;
                discrete[(size_t)t * K + bi] = 1.0f;
            } else sidx[wave * 16 + i] = 0;
        }
    }
    __syncthreads();

    for (int i = tid; i < 64 * (D / 4); i += 256) {
        int t = i >> 6;
        int c4 = i & 63;
        int bi = sidx[t];
        float4 v = ((const float4*)(cb + (size_t)bi * D))[c4];
        ((float4*)(quant + (size_t)(tok0 + t) * D))[c4] = v;
    }
}

// ---------------------------------------------------------------------------
extern "C" void kernel_launch(void* const* d_in, const int* in_sizes, int n_in,
                              void* d_out, int out_size, void* d_ws, size_t ws_size,
                              hipStream_t stream) {
    const float* x    = (const float*)d_in[0];   // [16,1024,256]
    const float* cb   = (const float*)d_in[1];   // [8192,256]
    const float* w    = (const float*)d_in[2];   // [256,128]
    const float* bias = (const float*)d_in[3];   // [128]

    float* out = (float*)d_out;
    float* discrete = out;                               // [16384, 8192]
    float* quant = out + (size_t)NTOK * K;               // [16384, 256]

    char* ws = (char*)d_ws;
    size_t off = 0;
    float* xproj = (float*)(ws + off); off += (size_t)NTOK * P * 4;
    float* cproj = (float*)(ws + off); off += (size_t)K * P * 4;
    float* xnorm = (float*)(ws + off); off += (size_t)NTOK * 4;
    float* cnorm = (float*)(ws + off); off += (size_t)K * 4;
    unsigned short* xh  = (unsigned short*)(ws + off); off += (size_t)NTOK * P * 2;
    unsigned short* chs = (unsigned short*)(ws + off); off += (size_t)K * P * 2;
    int* cnt  = (int*)(ws + off); off += (size_t)NTOK * 4;
    int* cand = (int*)(ws + off); off += (size_t)NTOK * CAPC * 4;

    proj_kernel<<<dim3(NROWS / 16), dim3(256), 0, stream>>>(
        x, cb, w, bias, xproj, cproj, xnorm, cnorm, xh, chs, cnt);

    minzero_collect_kernel<<<dim3(NTOK / 128, 4), dim3(256), 0, stream>>>(
        xh, chs, xnorm, cnorm, cnt, cand, discrete);

    rescorefinal_kernel<<<dim3(NTOK / 64), dim3(256), 0, stream>>>(
        xproj, cproj, xnorm, cnorm, cnt, cand, cb, discrete, quant);
}